// Round 4
// baseline (394.573 us; speedup 1.0000x reference)
//
#include <hip/hip_runtime.h>
#include <hip/hip_bf16.h>

// ---------------------------------------------------------------------------
// FCx2DetHead pipeline. R4 changes:
//  - split-K GEMMs write per-Z fp32 partial slabs (plain coalesced stores);
//    fused reduce_bias kernel does sum-over-Z + bias + optional relu + bf16
//    cast. Removes 7.3M device-scope atomicAdds (R3: WRITE_SIZE 80 MB, the
//    bottleneck) and the separate relu_cvt/bias-preinit kernels.
//  - BN=32 + larger Z: G1/G4 grids 1792 blocks (7 blocks/CU) for CU-level
//    latency overlap (R3 occupancy was grid-capped at 26%).
//  - partial-slab Z tiered on ws_size (constant per process -> graph-safe).
// ---------------------------------------------------------------------------

#define NROI 256
#define NB   8
#define INF  12544   // 256*49
#define DFC  1024
#define FCC  512

typedef __attribute__((ext_vector_type(8))) short short8;
typedef __attribute__((ext_vector_type(4))) float floatx4;

static __device__ __forceinline__ unsigned short f2bf(float f) {
    unsigned int u = __float_as_uint(f);
    unsigned int r = (u + 0x7fffu + ((u >> 16) & 1u)) >> 16;
    return (unsigned short)r;
}

// ---------------- transpose x (B,C,H,W) -> feat (B,H,W,C) -------------------
__global__ __launch_bounds__(256) void transpose_kernel(
        const float* __restrict__ x, float* __restrict__ xT) {
    __shared__ float t[32][33];
    int b  = blockIdx.z;
    int cb = blockIdx.y * 32;     // channel tile
    int lb = blockIdx.x * 32;     // hw tile (0..624)
    int tx = threadIdx.x & 31, ty = threadIdx.x >> 5;
#pragma unroll
    for (int r = 0; r < 4; ++r) {
        int c = cb + ty + r * 8, l = lb + tx;
        if (l < 625) t[ty + r * 8][tx] = x[(size_t)(b * 256 + c) * 625 + l];
    }
    __syncthreads();
#pragma unroll
    for (int r = 0; r < 4; ++r) {
        int l = lb + ty + r * 8, c = cb + tx;
        if (l < 625) xT[((size_t)b * 625 + l) * 256 + c] = t[tx][ty + r * 8];
    }
}

// ---------------- pool prep: per (roi,bin) 16-cell weight grid --------------
__global__ __launch_bounds__(256) void pool_prep(
        const float* __restrict__ rois, const float* __restrict__ off, int has_off,
        float* __restrict__ wbuf, int* __restrict__ bbuf) {
    __shared__ float g[256][16];
    const float SSC = (float)(25.0 / 255.0);
    int tid = threadIdx.x;
    int idx = blockIdx.x * 256 + tid;          // [0, 12544)
    int n = idx / 49;
    int bin = idx - n * 49;
    const float* r = rois + n * 5;
    int b = (int)r[0];
    float sw = rintf(r[1]) * SSC - 0.5f;
    float sh = rintf(r[2]) * SSC - 0.5f;
    float rw = fmaxf((rintf(r[3]) + 1.0f) * SSC - 0.5f - sw, 0.1f);
    float rh = fmaxf((rintf(r[4]) + 1.0f) * SSC - 0.5f - sh, 0.1f);
    float bw = rw / 7.0f, bh = rh / 7.0f;
    float bws = bw * 0.25f, bhs = bh * 0.25f;
    int ph = bin / 7, pw = bin - ph * 7;
    float tx = 0.f, ty = 0.f;
    if (has_off) {
        tx = off[n * 98 + bin] * 0.1f;
        ty = off[n * 98 + 49 + bin] * 0.1f;
    }
    float wstart = pw * bw + sw + tx * rw;
    float hstart = ph * bh + sh + ty * rh;
#pragma unroll
    for (int i = 0; i < 16; ++i) g[tid][i] = 0.f;
    int gy0 = 0, gx0 = 0, cnt = 0;
#pragma unroll
    for (int s = 0; s < 16; ++s) {
        float fx = wstart + (s & 3) * bws;
        float fy = hstart + (s >> 2) * bhs;
        bool valid = (fx >= -0.5f) && (fx <= 24.5f) && (fy >= -0.5f) && (fy <= 24.5f);
        float xc = fminf(fmaxf(fx, 0.f), 24.f);
        float yc = fminf(fmaxf(fy, 0.f), 24.f);
        float x0f = floorf(xc), y0f = floorf(yc);
        float dx = xc - x0f, dy = yc - y0f;
        int x0 = (int)x0f, y0 = (int)y0f;
        int x1 = (int)ceilf(xc), y1 = (int)ceilf(yc);
        if (s == 0) { gy0 = y0; gx0 = x0; }
        float w00 = (1.f - dx) * (1.f - dy), w01 = dx * (1.f - dy);
        float w10 = (1.f - dx) * dy,         w11 = dx * dy;
        if (!valid) { w00 = w01 = w10 = w11 = 0.f; }
        cnt += valid ? 1 : 0;
        int ry0 = (y0 - gy0) * 4, ry1 = (y1 - gy0) * 4;
        g[tid][ry0 + (x0 - gx0)] += w00;
        g[tid][ry0 + (x1 - gx0)] += w01;
        g[tid][ry1 + (x0 - gx0)] += w10;
        g[tid][ry1 + (x1 - gx0)] += w11;
    }
    float inv = 1.0f / fmaxf((float)cnt, 1.0f);
    float4* wp = (float4*)(wbuf + (size_t)idx * 16);
#pragma unroll
    for (int q = 0; q < 4; ++q)
        wp[q] = make_float4(g[tid][q * 4] * inv, g[tid][q * 4 + 1] * inv,
                            g[tid][q * 4 + 2] * inv, g[tid][q * 4 + 3] * inv);
    bbuf[idx] = gy0 | (gx0 << 8) | (b << 16);
}

// ---------------- pool gather ----------------------------------------------
__global__ __launch_bounds__(256) void pool_gather(
        const float* __restrict__ feat, const float* __restrict__ wbuf,
        const int* __restrict__ bbuf, unsigned short* __restrict__ P) {
    __shared__ unsigned short sOut[128 * 49];
    int q = blockIdx.x;            // channel half: 0 or 1
    int n = blockIdx.y;            // roi
    int tid = threadIdx.x;
    int wv = tid >> 6, lane = tid & 63;
    int cbase = q * 128 + lane * 2;

    for (int bin = wv; bin < 49; bin += 4) {
        int di = n * 49 + bin;
        int base = bbuf[di];
        int gy0 = base & 255, gx0 = (base >> 8) & 255, b = base >> 16;
        const float4* wp = (const float4*)(wbuf + (size_t)di * 16);
        float4 w0 = wp[0], w1 = wp[1], w2 = wp[2], w3 = wp[3];
        float ww[16] = { w0.x, w0.y, w0.z, w0.w, w1.x, w1.y, w1.z, w1.w,
                         w2.x, w2.y, w2.z, w2.w, w3.x, w3.y, w3.z, w3.w };
        int rowOff[4], colOff[4];
#pragma unroll
        for (int r = 0; r < 4; ++r) {
            rowOff[r] = min(gy0 + r, 24) * 25;
            colOff[r] = min(gx0 + r, 24);
        }
        int b625 = b * 625;
        float ax = 0.f, ay = 0.f;
#pragma unroll
        for (int cell = 0; cell < 16; ++cell) {
            int pix = b625 + rowOff[cell >> 2] + colOff[cell & 3];
            float2 v = *(const float2*)(feat + (size_t)pix * 256 + cbase);
            ax += ww[cell] * v.x;
            ay += ww[cell] * v.y;
        }
        sOut[(lane * 2) * 49 + bin] = f2bf(ax);
        sOut[(lane * 2 + 1) * 49 + bin] = f2bf(ay);
    }
    __syncthreads();
    const uint2* so = (const uint2*)sOut;
    uint2* dp = (uint2*)(P + (size_t)n * INF + q * 128 * 49);
    for (int i = tid; i < 128 * 49 / 4; i += 256) dp[i] = so[i];
}

// ---------------- split-K MFMA GEMM -> fp32 partial slabs -------------------
// C_part[z] = A(bf16,MxK-slice) * B(fp32,NxK-slice)^T, plain stores.
// Register-prefetch pipeline (tile k+1 loads overlap tile k's MFMA).
template <int BM, int BN>
__global__ __launch_bounds__(256) void gemm_nt_part(
        const unsigned short* __restrict__ A, const float* __restrict__ Bw,
        float* __restrict__ Cpart, int M, int N, int K, int kSteps) {
    constexpr int LDA = 40;                  // 16B-aligned row stride (80 B)
    __shared__ unsigned short As[BM * LDA];
    __shared__ unsigned short Bs[BN * LDA];
    const int tid = threadIdx.x;
    const int lane = tid & 63;
    const int wave = tid >> 6;
    const int wm = wave >> 1, wn = wave & 1;
    const int m0 = blockIdx.y * BM;
    const int n0 = blockIdx.x * BN;
    const int k0 = blockIdx.z * kSteps * 32;
    const int quad = lane >> 4;
    const int l16 = lane & 15;
    constexpr int FM = BM / 32, FN = BN / 32;
    constexpr int NA = BM * 4 / 256;   // uint4 A-loads per thread
    constexpr int NBq = BN * 8 / 256;  // float4 B-loads per thread

    floatx4 acc[FM][FN];
#pragma unroll
    for (int i = 0; i < FM; ++i)
#pragma unroll
        for (int j = 0; j < FN; ++j) acc[i][j] = (floatx4)0.f;

    uint4  ra[NA];
    float4 rb[NBq];
    auto loadTile = [&](int kk) {
#pragma unroll
        for (int i = 0; i < NA; ++i) {
            int idx = tid + i * 256, row = idx >> 2, qq = idx & 3;
            ra[i] = *(const uint4*)(A + (size_t)(m0 + row) * K + kk + qq * 8);
        }
#pragma unroll
        for (int i = 0; i < NBq; ++i) {
            int idx = tid + i * 256, row = idx >> 3, qq = idx & 7;
            rb[i] = *(const float4*)(Bw + (size_t)(n0 + row) * K + kk + qq * 4);
        }
    };

    loadTile(k0);
    for (int ks = 0; ks < kSteps; ++ks) {
#pragma unroll
        for (int i = 0; i < NA; ++i) {
            int idx = tid + i * 256, row = idx >> 2, qq = idx & 3;
            *(uint4*)(As + row * LDA + qq * 8) = ra[i];
        }
#pragma unroll
        for (int i = 0; i < NBq; ++i) {
            int idx = tid + i * 256, row = idx >> 3, qq = idx & 7;
            ushort4 h;
            h.x = f2bf(rb[i].x); h.y = f2bf(rb[i].y);
            h.z = f2bf(rb[i].z); h.w = f2bf(rb[i].w);
            *(ushort4*)(Bs + row * LDA + qq * 4) = h;
        }
        __syncthreads();
        if (ks + 1 < kSteps) loadTile(k0 + (ks + 1) * 32);   // overlap w/ MFMA
        short8 a[FM], bfr[FN];
#pragma unroll
        for (int i = 0; i < FM; ++i)
            a[i] = *(const short8*)(As + (wm * (BM / 2) + i * 16 + l16) * LDA + quad * 8);
#pragma unroll
        for (int j = 0; j < FN; ++j)
            bfr[j] = *(const short8*)(Bs + (wn * (BN / 2) + j * 16 + l16) * LDA + quad * 8);
#pragma unroll
        for (int i = 0; i < FM; ++i)
#pragma unroll
            for (int j = 0; j < FN; ++j)
                acc[i][j] = __builtin_amdgcn_mfma_f32_16x16x32_bf16(a[i], bfr[j], acc[i][j], 0, 0, 0);
        __syncthreads();
    }
    // epilogue: plain stores into this z's partial slab
    float* Cp = Cpart + (size_t)blockIdx.z * M * N;
#pragma unroll
    for (int i = 0; i < FM; ++i)
#pragma unroll
        for (int j = 0; j < FN; ++j) {
            int row0 = m0 + wm * (BM / 2) + i * 16 + quad * 4;
            int col = n0 + wn * (BN / 2) + j * 16 + l16;
#pragma unroll
            for (int rr = 0; rr < 4; ++rr)
                Cp[(size_t)(row0 + rr) * N + col] = acc[i][j][rr];
        }
}

// ---------------- reduce over Z + bias + optional relu + casts --------------
__global__ __launch_bounds__(256) void reduce_bias(
        const float* __restrict__ part, int zc, int mn4,
        const float* __restrict__ bias, int nmask, int relu,
        unsigned short* __restrict__ obf, float* __restrict__ of) {
    int idx = blockIdx.x * 256 + threadIdx.x;    // float4 index
    if (idx >= mn4) return;
    int idx4 = idx * 4;
    const float* bp = bias + (idx4 & nmask);
    float4 acc = *(const float4*)bp;
    const float4* p = (const float4*)part + idx;
    for (int z = 0; z < zc; ++z) {
        float4 v = p[(size_t)z * mn4];
        acc.x += v.x; acc.y += v.y; acc.z += v.z; acc.w += v.w;
    }
    if (relu) {
        acc.x = fmaxf(acc.x, 0.f); acc.y = fmaxf(acc.y, 0.f);
        acc.z = fmaxf(acc.z, 0.f); acc.w = fmaxf(acc.w, 0.f);
    }
    if (obf) {
        ushort4 h;
        h.x = f2bf(acc.x); h.y = f2bf(acc.y); h.z = f2bf(acc.z); h.w = f2bf(acc.w);
        *(ushort4*)(obf + idx4) = h;
    }
    if (of) *(float4*)(of + idx4) = acc;
}

// ---------------- G3: off = relu(h2) @ w3^T + b3  (256 x 98) ----------------
__global__ __launch_bounds__(128) void fc_small(
        const float* __restrict__ h2, const float* __restrict__ w3,
        const float* __restrict__ b3, float* __restrict__ out) {
    __shared__ float shl[1024];
    int n = blockIdx.x, tid = threadIdx.x;
    for (int i = tid; i < 1024; i += 128) shl[i] = fmaxf(h2[(size_t)n * 1024 + i], 0.f);
    __syncthreads();
    if (tid < 98) {
        float acc = b3[tid];
        const float* w = w3 + (size_t)tid * 1024;
        for (int k = 0; k < 1024; k += 4) {
            float4 wv = *(const float4*)(w + k);
            acc += shl[k] * wv.x + shl[k + 1] * wv.y + shl[k + 2] * wv.z + shl[k + 3] * wv.w;
        }
        out[n * 98 + tid] = acc;
    }
}

// ---------------- G6: out = relu(h4) @ box_w^T + box_b  (256 x 4) -----------
__global__ __launch_bounds__(64) void head_kernel(
        const float* __restrict__ h4, const float* __restrict__ bw,
        const float* __restrict__ bb, float* __restrict__ out) {
    int n = blockIdx.x, t = threadIdx.x;
    float a0 = 0, a1 = 0, a2 = 0, a3 = 0;
    for (int k = t; k < 512; k += 64) {
        float v = fmaxf(h4[(size_t)n * 512 + k], 0.f);
        a0 += v * bw[k]; a1 += v * bw[512 + k];
        a2 += v * bw[1024 + k]; a3 += v * bw[1536 + k];
    }
#pragma unroll
    for (int o = 32; o > 0; o >>= 1) {
        a0 += __shfl_down(a0, o); a1 += __shfl_down(a1, o);
        a2 += __shfl_down(a2, o); a3 += __shfl_down(a3, o);
    }
    if (t == 0) {
        out[n * 4 + 0] = a0 + bb[0]; out[n * 4 + 1] = a1 + bb[1];
        out[n * 4 + 2] = a2 + bb[2]; out[n * 4 + 3] = a3 + bb[3];
    }
}

// ---------------------------------------------------------------------------
extern "C" void kernel_launch(void* const* d_in, const int* in_sizes, int n_in,
                              void* d_out, int out_size, void* d_ws, size_t ws_size,
                              hipStream_t stream) {
    const float* x      = (const float*)d_in[0];
    const float* rois   = (const float*)d_in[1];
    const float* off_w1 = (const float*)d_in[2];
    const float* off_b1 = (const float*)d_in[3];
    const float* off_w2 = (const float*)d_in[4];
    const float* off_b2 = (const float*)d_in[5];
    const float* off_w3 = (const float*)d_in[6];
    const float* off_b3 = (const float*)d_in[7];
    const float* fc1_w  = (const float*)d_in[8];
    const float* fc1_b  = (const float*)d_in[9];
    const float* fc2_w  = (const float*)d_in[10];
    const float* fc2_b  = (const float*)d_in[11];
    const float* box_w  = (const float*)d_in[12];
    const float* box_b  = (const float*)d_in[13];
    float* out = (float*)d_out;

    char* ws = (char*)d_ws;
    size_t o = 0;
    auto carve = [&](size_t bytes) { char* p = ws + o; o += (bytes + 255) & ~(size_t)255; return p; };
    float*          xT   = (float*)carve((size_t)NB * 625 * 256 * 4);   // 5.12 MB
    unsigned short* P    = (unsigned short*)carve((size_t)NROI * INF * 2); // shared p0/p1
    unsigned short* h1b  = (unsigned short*)carve((size_t)NROI * DFC * 2);
    float*          h2   = (float*)carve((size_t)NROI * DFC * 4);
    float*          offb = (float*)carve((size_t)NROI * 98 * 4);
    unsigned short* h3b  = (unsigned short*)carve((size_t)NROI * FCC * 2);
    float*          h4   = (float*)carve((size_t)NROI * FCC * 4);
    float*          wbuf = (float*)carve((size_t)NROI * 49 * 16 * 4);   // 803 KB
    int*            bbuf = (int*)carve((size_t)NROI * 49 * 4);
    size_t fixed = o;
    const size_t SLAB = (size_t)NROI * DFC * 4;   // 1 MB per G1-sized slice
    // tier the split-K depth on available scratch (ws_size is constant -> same
    // work every call, graph-safe)
    int zg1;
    if      (ws_size >= fixed + 28 * SLAB) zg1 = 28;
    else if (ws_size >= fixed + 14 * SLAB) zg1 = 14;
    else if (ws_size >= fixed +  7 * SLAB) zg1 = 7;
    else                                   zg1 = 4;
    int zg4 = zg1 * 2;                 // 0.5 MB slabs -> same byte footprint
    int zg2 = (zg1 >= 14) ? 8 : 4;
    float* part = (float*)carve((size_t)zg1 * SLAB);

    // 1. channels-last transpose of x
    transpose_kernel<<<dim3(20, 8, 8), 256, 0, stream>>>(x, xT);
    // 2. pool pass 0 (zero offsets)
    pool_prep<<<49, 256, 0, stream>>>(rois, nullptr, 0, wbuf, bbuf);
    pool_gather<<<dim3(2, NROI), 256, 0, stream>>>(xT, wbuf, bbuf, P);
    // 3. G1 partials + reduce(+b1+relu) -> h1b
    gemm_nt_part<128, 32><<<dim3(32, 2, zg1), 256, 0, stream>>>(P, off_w1, part, NROI, DFC, INF, 392 / zg1);
    reduce_bias<<<256, 256, 0, stream>>>(part, zg1, NROI * DFC / 4, off_b1, DFC - 1, 1, h1b, nullptr);
    // 4. G2 partials + reduce(+b2) -> h2 (fp32; fc_small applies relu)
    gemm_nt_part<128, 32><<<dim3(32, 2, zg2), 256, 0, stream>>>(h1b, off_w2, part, NROI, DFC, DFC, 32 / zg2);
    reduce_bias<<<256, 256, 0, stream>>>(part, zg2, NROI * DFC / 4, off_b2, DFC - 1, 0, nullptr, h2);
    // 5. G3: offb = relu(h2) @ w3^T + b3
    fc_small<<<NROI, 128, 0, stream>>>(h2, off_w3, off_b3, offb);
    // 6. pool pass 1 (learned offsets), reuses P
    pool_prep<<<49, 256, 0, stream>>>(rois, offb, 1, wbuf, bbuf);
    pool_gather<<<dim3(2, NROI), 256, 0, stream>>>(xT, wbuf, bbuf, P);
    // 7. G4 partials + reduce(+fc1_b+relu) -> h3b
    gemm_nt_part<128, 32><<<dim3(16, 2, zg4), 256, 0, stream>>>(P, fc1_w, part, NROI, FCC, INF, 392 / zg4);
    reduce_bias<<<128, 256, 0, stream>>>(part, zg4, NROI * FCC / 4, fc1_b, FCC - 1, 1, h3b, nullptr);
    // 8. G5 partials + reduce(+fc2_b) -> h4 (fp32; head applies relu)
    gemm_nt_part<64, 32><<<dim3(16, 4, 4), 256, 0, stream>>>(h3b, fc2_w, part, NROI, FCC, FCC, 4);
    reduce_bias<<<128, 256, 0, stream>>>(part, 4, NROI * FCC / 4, fc2_b, FCC - 1, 0, nullptr, h4);
    // 9. G6: out = relu(h4) @ box_w^T + box_b
    head_kernel<<<NROI, 64, 0, stream>>>(h4, box_w, box_b, out);
}

// Round 5
// 339.400 us; speedup vs baseline: 1.1626x; 1.1626x over previous
//
#include <hip/hip_runtime.h>
#include <hip/hip_bf16.h>

// ---------------------------------------------------------------------------
// FCx2DetHead pipeline. R5 changes (R4 regressed on partial-store write
// amplification: WRITE_SIZE 122 MB, hbm-bound at 2 TB/s):
//  - GEMM BM=256 = full M: no M-split -> B weights read exactly once.
//    4 waves x 64 rows, FM=FN=4, 16 MFMA/k-step.
//  - Epilogue stores row-major with j inner: each wave writes full 256-B
//    row spans (complete cache lines) -> no partial-sector amplification.
//  - Z: G1 (16,1,28) s14, G4 (8,1,28) s14, G2 (16,1,4) s8, G5 (8,1,4) s4.
// ---------------------------------------------------------------------------

#define NROI 256
#define NB   8
#define INF  12544   // 256*49
#define DFC  1024
#define FCC  512

typedef __attribute__((ext_vector_type(8))) short short8;
typedef __attribute__((ext_vector_type(4))) float floatx4;

static __device__ __forceinline__ unsigned short f2bf(float f) {
    unsigned int u = __float_as_uint(f);
    unsigned int r = (u + 0x7fffu + ((u >> 16) & 1u)) >> 16;
    return (unsigned short)r;
}

// ---------------- transpose x (B,C,H,W) -> feat (B,H,W,C) -------------------
__global__ __launch_bounds__(256) void transpose_kernel(
        const float* __restrict__ x, float* __restrict__ xT) {
    __shared__ float t[32][33];
    int b  = blockIdx.z;
    int cb = blockIdx.y * 32;     // channel tile
    int lb = blockIdx.x * 32;     // hw tile (0..624)
    int tx = threadIdx.x & 31, ty = threadIdx.x >> 5;
#pragma unroll
    for (int r = 0; r < 4; ++r) {
        int c = cb + ty + r * 8, l = lb + tx;
        if (l < 625) t[ty + r * 8][tx] = x[(size_t)(b * 256 + c) * 625 + l];
    }
    __syncthreads();
#pragma unroll
    for (int r = 0; r < 4; ++r) {
        int l = lb + ty + r * 8, c = cb + tx;
        if (l < 625) xT[((size_t)b * 625 + l) * 256 + c] = t[tx][ty + r * 8];
    }
}

// ---------------- pool prep: per (roi,bin) 16-cell weight grid --------------
__global__ __launch_bounds__(256) void pool_prep(
        const float* __restrict__ rois, const float* __restrict__ off, int has_off,
        float* __restrict__ wbuf, int* __restrict__ bbuf) {
    __shared__ float g[256][16];
    const float SSC = (float)(25.0 / 255.0);
    int tid = threadIdx.x;
    int idx = blockIdx.x * 256 + tid;          // [0, 12544)
    int n = idx / 49;
    int bin = idx - n * 49;
    const float* r = rois + n * 5;
    int b = (int)r[0];
    float sw = rintf(r[1]) * SSC - 0.5f;
    float sh = rintf(r[2]) * SSC - 0.5f;
    float rw = fmaxf((rintf(r[3]) + 1.0f) * SSC - 0.5f - sw, 0.1f);
    float rh = fmaxf((rintf(r[4]) + 1.0f) * SSC - 0.5f - sh, 0.1f);
    float bw = rw / 7.0f, bh = rh / 7.0f;
    float bws = bw * 0.25f, bhs = bh * 0.25f;
    int ph = bin / 7, pw = bin - ph * 7;
    float tx = 0.f, ty = 0.f;
    if (has_off) {
        tx = off[n * 98 + bin] * 0.1f;
        ty = off[n * 98 + 49 + bin] * 0.1f;
    }
    float wstart = pw * bw + sw + tx * rw;
    float hstart = ph * bh + sh + ty * rh;
#pragma unroll
    for (int i = 0; i < 16; ++i) g[tid][i] = 0.f;
    int gy0 = 0, gx0 = 0, cnt = 0;
#pragma unroll
    for (int s = 0; s < 16; ++s) {
        float fx = wstart + (s & 3) * bws;
        float fy = hstart + (s >> 2) * bhs;
        bool valid = (fx >= -0.5f) && (fx <= 24.5f) && (fy >= -0.5f) && (fy <= 24.5f);
        float xc = fminf(fmaxf(fx, 0.f), 24.f);
        float yc = fminf(fmaxf(fy, 0.f), 24.f);
        float x0f = floorf(xc), y0f = floorf(yc);
        float dx = xc - x0f, dy = yc - y0f;
        int x0 = (int)x0f, y0 = (int)y0f;
        int x1 = (int)ceilf(xc), y1 = (int)ceilf(yc);
        if (s == 0) { gy0 = y0; gx0 = x0; }
        float w00 = (1.f - dx) * (1.f - dy), w01 = dx * (1.f - dy);
        float w10 = (1.f - dx) * dy,         w11 = dx * dy;
        if (!valid) { w00 = w01 = w10 = w11 = 0.f; }
        cnt += valid ? 1 : 0;
        int ry0 = (y0 - gy0) * 4, ry1 = (y1 - gy0) * 4;
        g[tid][ry0 + (x0 - gx0)] += w00;
        g[tid][ry0 + (x1 - gx0)] += w01;
        g[tid][ry1 + (x0 - gx0)] += w10;
        g[tid][ry1 + (x1 - gx0)] += w11;
    }
    float inv = 1.0f / fmaxf((float)cnt, 1.0f);
    float4* wp = (float4*)(wbuf + (size_t)idx * 16);
#pragma unroll
    for (int q = 0; q < 4; ++q)
        wp[q] = make_float4(g[tid][q * 4] * inv, g[tid][q * 4 + 1] * inv,
                            g[tid][q * 4 + 2] * inv, g[tid][q * 4 + 3] * inv);
    bbuf[idx] = gy0 | (gx0 << 8) | (b << 16);
}

// ---------------- pool gather ----------------------------------------------
__global__ __launch_bounds__(256) void pool_gather(
        const float* __restrict__ feat, const float* __restrict__ wbuf,
        const int* __restrict__ bbuf, unsigned short* __restrict__ P) {
    __shared__ unsigned short sOut[128 * 49];
    int q = blockIdx.x;            // channel half: 0 or 1
    int n = blockIdx.y;            // roi
    int tid = threadIdx.x;
    int wv = tid >> 6, lane = tid & 63;
    int cbase = q * 128 + lane * 2;

    for (int bin = wv; bin < 49; bin += 4) {
        int di = n * 49 + bin;
        int base = bbuf[di];
        int gy0 = base & 255, gx0 = (base >> 8) & 255, b = base >> 16;
        const float4* wp = (const float4*)(wbuf + (size_t)di * 16);
        float4 w0 = wp[0], w1 = wp[1], w2 = wp[2], w3 = wp[3];
        float ww[16] = { w0.x, w0.y, w0.z, w0.w, w1.x, w1.y, w1.z, w1.w,
                         w2.x, w2.y, w2.z, w2.w, w3.x, w3.y, w3.z, w3.w };
        int rowOff[4], colOff[4];
#pragma unroll
        for (int r = 0; r < 4; ++r) {
            rowOff[r] = min(gy0 + r, 24) * 25;
            colOff[r] = min(gx0 + r, 24);
        }
        int b625 = b * 625;
        float ax = 0.f, ay = 0.f;
#pragma unroll
        for (int cell = 0; cell < 16; ++cell) {
            int pix = b625 + rowOff[cell >> 2] + colOff[cell & 3];
            float2 v = *(const float2*)(feat + (size_t)pix * 256 + cbase);
            ax += ww[cell] * v.x;
            ay += ww[cell] * v.y;
        }
        sOut[(lane * 2) * 49 + bin] = f2bf(ax);
        sOut[(lane * 2 + 1) * 49 + bin] = f2bf(ay);
    }
    __syncthreads();
    const uint2* so = (const uint2*)sOut;
    uint2* dp = (uint2*)(P + (size_t)n * INF + q * 128 * 49);
    for (int i = tid; i < 128 * 49 / 4; i += 256) dp[i] = so[i];
}

// ---------------- split-K MFMA GEMM (BM=256=M) -> fp32 partial slabs --------
// 4 waves x 64 rows each, BN=64 cols: FM=4, FN=4, 16 MFMA per k-step.
// Register-prefetch pipeline; epilogue stores full 256-B row spans.
template <int BN>
__global__ __launch_bounds__(256) void gemm_nt_part(
        const unsigned short* __restrict__ A, const float* __restrict__ Bw,
        float* __restrict__ Cpart, int N, int K, int kSteps) {
    constexpr int BM = 256;
    constexpr int LDA = 40;                  // 16B-aligned row stride (80 B)
    __shared__ unsigned short As[BM * LDA];  // 20.0 KB
    __shared__ unsigned short Bs[BN * LDA];  //  5.0 KB
    const int tid = threadIdx.x;
    const int lane = tid & 63;
    const int wave = tid >> 6;               // row-group owner
    const int n0 = blockIdx.x * BN;
    const int k0 = blockIdx.z * kSteps * 32;
    const int quad = lane >> 4;
    const int l16 = lane & 15;
    constexpr int FM = 4, FN = BN / 16;
    constexpr int NA = BM * 4 / 256;   // 4 uint4 A-loads per thread
    constexpr int NBq = BN * 8 / 256;  // 2 float4 B-loads per thread

    floatx4 acc[FM][FN];
#pragma unroll
    for (int i = 0; i < FM; ++i)
#pragma unroll
        for (int j = 0; j < FN; ++j) acc[i][j] = (floatx4)0.f;

    uint4  ra[NA];
    float4 rb[NBq];
    auto loadTile = [&](int kk) {
#pragma unroll
        for (int i = 0; i < NA; ++i) {
            int idx = tid + i * 256, row = idx >> 2, qq = idx & 3;
            ra[i] = *(const uint4*)(A + (size_t)row * K + kk + qq * 8);
        }
#pragma unroll
        for (int i = 0; i < NBq; ++i) {
            int idx = tid + i * 256, row = idx >> 3, qq = idx & 7;
            rb[i] = *(const float4*)(Bw + (size_t)(n0 + row) * K + kk + qq * 4);
        }
    };

    loadTile(k0);
    for (int ks = 0; ks < kSteps; ++ks) {
#pragma unroll
        for (int i = 0; i < NA; ++i) {
            int idx = tid + i * 256, row = idx >> 2, qq = idx & 3;
            *(uint4*)(As + row * LDA + qq * 8) = ra[i];
        }
#pragma unroll
        for (int i = 0; i < NBq; ++i) {
            int idx = tid + i * 256, row = idx >> 3, qq = idx & 7;
            ushort4 h;
            h.x = f2bf(rb[i].x); h.y = f2bf(rb[i].y);
            h.z = f2bf(rb[i].z); h.w = f2bf(rb[i].w);
            *(ushort4*)(Bs + row * LDA + qq * 4) = h;
        }
        __syncthreads();
        if (ks + 1 < kSteps) loadTile(k0 + (ks + 1) * 32);   // overlap w/ MFMA
        short8 a[FM], bfr[FN];
#pragma unroll
        for (int i = 0; i < FM; ++i)
            a[i] = *(const short8*)(As + (wave * 64 + i * 16 + l16) * LDA + quad * 8);
#pragma unroll
        for (int j = 0; j < FN; ++j)
            bfr[j] = *(const short8*)(Bs + (j * 16 + l16) * LDA + quad * 8);
#pragma unroll
        for (int i = 0; i < FM; ++i)
#pragma unroll
            for (int j = 0; j < FN; ++j)
                acc[i][j] = __builtin_amdgcn_mfma_f32_16x16x32_bf16(a[i], bfr[j], acc[i][j], 0, 0, 0);
        __syncthreads();
    }
    // epilogue: row-major, j inner -> full 256-B contiguous span per row
    float* Cp = Cpart + (size_t)blockIdx.z * BM * N;
#pragma unroll
    for (int i = 0; i < FM; ++i)
#pragma unroll
        for (int rr = 0; rr < 4; ++rr) {
            int row = wave * 64 + i * 16 + quad * 4 + rr;
            float* cr = Cp + (size_t)row * N + n0;
#pragma unroll
            for (int j = 0; j < FN; ++j)
                cr[j * 16 + l16] = acc[i][j][rr];
        }
}

// ---------------- reduce over Z + bias + optional relu + casts --------------
__global__ __launch_bounds__(256) void reduce_bias(
        const float* __restrict__ part, int zc, int mn4,
        const float* __restrict__ bias, int nmask, int relu,
        unsigned short* __restrict__ obf, float* __restrict__ of) {
    int idx = blockIdx.x * 256 + threadIdx.x;    // float4 index
    if (idx >= mn4) return;
    int idx4 = idx * 4;
    const float* bp = bias + (idx4 & nmask);
    float4 acc = *(const float4*)bp;
    const float4* p = (const float4*)part + idx;
    for (int z = 0; z < zc; ++z) {
        float4 v = p[(size_t)z * mn4];
        acc.x += v.x; acc.y += v.y; acc.z += v.z; acc.w += v.w;
    }
    if (relu) {
        acc.x = fmaxf(acc.x, 0.f); acc.y = fmaxf(acc.y, 0.f);
        acc.z = fmaxf(acc.z, 0.f); acc.w = fmaxf(acc.w, 0.f);
    }
    if (obf) {
        ushort4 h;
        h.x = f2bf(acc.x); h.y = f2bf(acc.y); h.z = f2bf(acc.z); h.w = f2bf(acc.w);
        *(ushort4*)(obf + idx4) = h;
    }
    if (of) *(float4*)(of + idx4) = acc;
}

// ---------------- G3: off = relu(h2) @ w3^T + b3  (256 x 98) ----------------
__global__ __launch_bounds__(128) void fc_small(
        const float* __restrict__ h2, const float* __restrict__ w3,
        const float* __restrict__ b3, float* __restrict__ out) {
    __shared__ float shl[1024];
    int n = blockIdx.x, tid = threadIdx.x;
    for (int i = tid; i < 1024; i += 128) shl[i] = fmaxf(h2[(size_t)n * 1024 + i], 0.f);
    __syncthreads();
    if (tid < 98) {
        float acc = b3[tid];
        const float* w = w3 + (size_t)tid * 1024;
        for (int k = 0; k < 1024; k += 4) {
            float4 wv = *(const float4*)(w + k);
            acc += shl[k] * wv.x + shl[k + 1] * wv.y + shl[k + 2] * wv.z + shl[k + 3] * wv.w;
        }
        out[n * 98 + tid] = acc;
    }
}

// ---------------- G6: out = relu(h4) @ box_w^T + box_b  (256 x 4) -----------
__global__ __launch_bounds__(64) void head_kernel(
        const float* __restrict__ h4, const float* __restrict__ bw,
        const float* __restrict__ bb, float* __restrict__ out) {
    int n = blockIdx.x, t = threadIdx.x;
    float a0 = 0, a1 = 0, a2 = 0, a3 = 0;
    for (int k = t; k < 512; k += 64) {
        float v = fmaxf(h4[(size_t)n * 512 + k], 0.f);
        a0 += v * bw[k]; a1 += v * bw[512 + k];
        a2 += v * bw[1024 + k]; a3 += v * bw[1536 + k];
    }
#pragma unroll
    for (int o = 32; o > 0; o >>= 1) {
        a0 += __shfl_down(a0, o); a1 += __shfl_down(a1, o);
        a2 += __shfl_down(a2, o); a3 += __shfl_down(a3, o);
    }
    if (t == 0) {
        out[n * 4 + 0] = a0 + bb[0]; out[n * 4 + 1] = a1 + bb[1];
        out[n * 4 + 2] = a2 + bb[2]; out[n * 4 + 3] = a3 + bb[3];
    }
}

// ---------------------------------------------------------------------------
extern "C" void kernel_launch(void* const* d_in, const int* in_sizes, int n_in,
                              void* d_out, int out_size, void* d_ws, size_t ws_size,
                              hipStream_t stream) {
    const float* x      = (const float*)d_in[0];
    const float* rois   = (const float*)d_in[1];
    const float* off_w1 = (const float*)d_in[2];
    const float* off_b1 = (const float*)d_in[3];
    const float* off_w2 = (const float*)d_in[4];
    const float* off_b2 = (const float*)d_in[5];
    const float* off_w3 = (const float*)d_in[6];
    const float* off_b3 = (const float*)d_in[7];
    const float* fc1_w  = (const float*)d_in[8];
    const float* fc1_b  = (const float*)d_in[9];
    const float* fc2_w  = (const float*)d_in[10];
    const float* fc2_b  = (const float*)d_in[11];
    const float* box_w  = (const float*)d_in[12];
    const float* box_b  = (const float*)d_in[13];
    float* out = (float*)d_out;

    char* ws = (char*)d_ws;
    size_t o = 0;
    auto carve = [&](size_t bytes) { char* p = ws + o; o += (bytes + 255) & ~(size_t)255; return p; };
    float*          xT   = (float*)carve((size_t)NB * 625 * 256 * 4);   // 5.12 MB
    unsigned short* P    = (unsigned short*)carve((size_t)NROI * INF * 2); // shared p0/p1
    unsigned short* h1b  = (unsigned short*)carve((size_t)NROI * DFC * 2);
    float*          h2   = (float*)carve((size_t)NROI * DFC * 4);
    float*          offb = (float*)carve((size_t)NROI * 98 * 4);
    unsigned short* h3b  = (unsigned short*)carve((size_t)NROI * FCC * 2);
    float*          h4   = (float*)carve((size_t)NROI * FCC * 4);
    float*          wbuf = (float*)carve((size_t)NROI * 49 * 16 * 4);   // 803 KB
    int*            bbuf = (int*)carve((size_t)NROI * 49 * 4);
    size_t fixed = o;
    const size_t SLAB = (size_t)NROI * DFC * 4;   // 1 MB (G1/G2-sized slice)
    // tier the split-K depth on available scratch (ws_size constant -> graph-safe)
    int zg1;
    if      (ws_size >= fixed + 28 * SLAB) zg1 = 28;
    else if (ws_size >= fixed + 14 * SLAB) zg1 = 14;
    else                                   zg1 = 7;
    float* part = (float*)carve((size_t)zg1 * SLAB);

    // 1. channels-last transpose of x
    transpose_kernel<<<dim3(20, 8, 8), 256, 0, stream>>>(x, xT);
    // 2. pool pass 0 (zero offsets)
    pool_prep<<<49, 256, 0, stream>>>(rois, nullptr, 0, wbuf, bbuf);
    pool_gather<<<dim3(2, NROI), 256, 0, stream>>>(xT, wbuf, bbuf, P);
    // 3. G1 partials + reduce(+b1+relu) -> h1b     (256x12544x1024)
    gemm_nt_part<64><<<dim3(16, 1, zg1), 256, 0, stream>>>(P, off_w1, part, DFC, INF, 392 / zg1);
    reduce_bias<<<256, 256, 0, stream>>>(part, zg1, NROI * DFC / 4, off_b1, DFC - 1, 1, h1b, nullptr);
    // 4. G2 partials + reduce(+b2) -> h2 (fp32; fc_small applies relu)
    gemm_nt_part<64><<<dim3(16, 1, 4), 256, 0, stream>>>(h1b, off_w2, part, DFC, DFC, 8);
    reduce_bias<<<256, 256, 0, stream>>>(part, 4, NROI * DFC / 4, off_b2, DFC - 1, 0, nullptr, h2);
    // 5. G3: offb = relu(h2) @ w3^T + b3
    fc_small<<<NROI, 128, 0, stream>>>(h2, off_w3, off_b3, offb);
    // 6. pool pass 1 (learned offsets), reuses P
    pool_prep<<<49, 256, 0, stream>>>(rois, offb, 1, wbuf, bbuf);
    pool_gather<<<dim3(2, NROI), 256, 0, stream>>>(xT, wbuf, bbuf, P);
    // 7. G4 partials + reduce(+fc1_b+relu) -> h3b  (256x12544x512)
    gemm_nt_part<64><<<dim3(8, 1, zg1), 256, 0, stream>>>(P, fc1_w, part, FCC, INF, 392 / zg1);
    reduce_bias<<<128, 256, 0, stream>>>(part, zg1, NROI * FCC / 4, fc1_b, FCC - 1, 1, h3b, nullptr);
    // 8. G5 partials + reduce(+fc2_b) -> h4 (fp32; head applies relu)
    gemm_nt_part<64><<<dim3(8, 1, 4), 256, 0, stream>>>(h3b, fc2_w, part, FCC, FCC, 4);
    reduce_bias<<<128, 256, 0, stream>>>(part, 4, NROI * FCC / 4, fc2_b, FCC - 1, 0, nullptr, h4);
    // 9. G6: out = relu(h4) @ box_w^T + box_b
    head_kernel<<<NROI, 64, 0, stream>>>(h4, box_w, box_b, out);
}

// Round 6
// 315.450 us; speedup vs baseline: 1.2508x; 1.0759x over previous
//
#include <hip/hip_runtime.h>
#include <hip/hip_bf16.h>

// ---------------------------------------------------------------------------
// FCx2DetHead pipeline. R6 changes (R5: VGPR_Count=64 showed acc spilled to
// AGPRs and staging loads serialized -> ~900cyc x 6 exposed per k-step):
//  - GEMM A-staging via __builtin_amdgcn_global_load_lds width=16 (zero VGPR,
//    async DMA). Unpadded As with XOR k-group swizzle (applied on the global
//    address) -> 2-way LDS conflicts only (free).
//  - BN=32: acc=32 VGPR, B staging = one float4/thread. ~90 VGPR total.
//  - m97-style 2-barrier K-loop; cross-block overlap (896/448 blocks) hides
//    the vmcnt drain at the barrier.
// ---------------------------------------------------------------------------

#define NROI 256
#define NB   8
#define INF  12544   // 256*49
#define DFC  1024
#define FCC  512

typedef __attribute__((ext_vector_type(8))) short short8;
typedef __attribute__((ext_vector_type(4))) float floatx4;

static __device__ __forceinline__ unsigned short f2bf(float f) {
    unsigned int u = __float_as_uint(f);
    unsigned int r = (u + 0x7fffu + ((u >> 16) & 1u)) >> 16;
    return (unsigned short)r;
}

static __device__ __forceinline__ void async_copy16(const void* g, void* l) {
    __builtin_amdgcn_global_load_lds(
        (const __attribute__((address_space(1))) unsigned int*)g,
        (__attribute__((address_space(3))) unsigned int*)l, 16, 0, 0);
}

// ---------------- transpose x (B,C,H,W) -> feat (B,H,W,C) -------------------
__global__ __launch_bounds__(256) void transpose_kernel(
        const float* __restrict__ x, float* __restrict__ xT) {
    __shared__ float t[32][33];
    int b  = blockIdx.z;
    int cb = blockIdx.y * 32;     // channel tile
    int lb = blockIdx.x * 32;     // hw tile (0..624)
    int tx = threadIdx.x & 31, ty = threadIdx.x >> 5;
#pragma unroll
    for (int r = 0; r < 4; ++r) {
        int c = cb + ty + r * 8, l = lb + tx;
        if (l < 625) t[ty + r * 8][tx] = x[(size_t)(b * 256 + c) * 625 + l];
    }
    __syncthreads();
#pragma unroll
    for (int r = 0; r < 4; ++r) {
        int l = lb + ty + r * 8, c = cb + tx;
        if (l < 625) xT[((size_t)b * 625 + l) * 256 + c] = t[tx][ty + r * 8];
    }
}

// ---------------- pool prep: per (roi,bin) 16-cell weight grid --------------
__global__ __launch_bounds__(256) void pool_prep(
        const float* __restrict__ rois, const float* __restrict__ off, int has_off,
        float* __restrict__ wbuf, int* __restrict__ bbuf) {
    __shared__ float g[256][16];
    const float SSC = (float)(25.0 / 255.0);
    int tid = threadIdx.x;
    int idx = blockIdx.x * 256 + tid;          // [0, 12544)
    int n = idx / 49;
    int bin = idx - n * 49;
    const float* r = rois + n * 5;
    int b = (int)r[0];
    float sw = rintf(r[1]) * SSC - 0.5f;
    float sh = rintf(r[2]) * SSC - 0.5f;
    float rw = fmaxf((rintf(r[3]) + 1.0f) * SSC - 0.5f - sw, 0.1f);
    float rh = fmaxf((rintf(r[4]) + 1.0f) * SSC - 0.5f - sh, 0.1f);
    float bw = rw / 7.0f, bh = rh / 7.0f;
    float bws = bw * 0.25f, bhs = bh * 0.25f;
    int ph = bin / 7, pw = bin - ph * 7;
    float tx = 0.f, ty = 0.f;
    if (has_off) {
        tx = off[n * 98 + bin] * 0.1f;
        ty = off[n * 98 + 49 + bin] * 0.1f;
    }
    float wstart = pw * bw + sw + tx * rw;
    float hstart = ph * bh + sh + ty * rh;
#pragma unroll
    for (int i = 0; i < 16; ++i) g[tid][i] = 0.f;
    int gy0 = 0, gx0 = 0, cnt = 0;
#pragma unroll
    for (int s = 0; s < 16; ++s) {
        float fx = wstart + (s & 3) * bws;
        float fy = hstart + (s >> 2) * bhs;
        bool valid = (fx >= -0.5f) && (fx <= 24.5f) && (fy >= -0.5f) && (fy <= 24.5f);
        float xc = fminf(fmaxf(fx, 0.f), 24.f);
        float yc = fminf(fmaxf(fy, 0.f), 24.f);
        float x0f = floorf(xc), y0f = floorf(yc);
        float dx = xc - x0f, dy = yc - y0f;
        int x0 = (int)x0f, y0 = (int)y0f;
        int x1 = (int)ceilf(xc), y1 = (int)ceilf(yc);
        if (s == 0) { gy0 = y0; gx0 = x0; }
        float w00 = (1.f - dx) * (1.f - dy), w01 = dx * (1.f - dy);
        float w10 = (1.f - dx) * dy,         w11 = dx * dy;
        if (!valid) { w00 = w01 = w10 = w11 = 0.f; }
        cnt += valid ? 1 : 0;
        int ry0 = (y0 - gy0) * 4, ry1 = (y1 - gy0) * 4;
        g[tid][ry0 + (x0 - gx0)] += w00;
        g[tid][ry0 + (x1 - gx0)] += w01;
        g[tid][ry1 + (x0 - gx0)] += w10;
        g[tid][ry1 + (x1 - gx0)] += w11;
    }
    float inv = 1.0f / fmaxf((float)cnt, 1.0f);
    float4* wp = (float4*)(wbuf + (size_t)idx * 16);
#pragma unroll
    for (int q = 0; q < 4; ++q)
        wp[q] = make_float4(g[tid][q * 4] * inv, g[tid][q * 4 + 1] * inv,
                            g[tid][q * 4 + 2] * inv, g[tid][q * 4 + 3] * inv);
    bbuf[idx] = gy0 | (gx0 << 8) | (b << 16);
}

// ---------------- pool gather ----------------------------------------------
__global__ __launch_bounds__(256) void pool_gather(
        const float* __restrict__ feat, const float* __restrict__ wbuf,
        const int* __restrict__ bbuf, unsigned short* __restrict__ P) {
    __shared__ unsigned short sOut[128 * 49];
    int q = blockIdx.x;            // channel half: 0 or 1
    int n = blockIdx.y;            // roi
    int tid = threadIdx.x;
    int wv = tid >> 6, lane = tid & 63;
    int cbase = q * 128 + lane * 2;

    for (int bin = wv; bin < 49; bin += 4) {
        int di = n * 49 + bin;
        int base = bbuf[di];
        int gy0 = base & 255, gx0 = (base >> 8) & 255, b = base >> 16;
        const float4* wp = (const float4*)(wbuf + (size_t)di * 16);
        float4 w0 = wp[0], w1 = wp[1], w2 = wp[2], w3 = wp[3];
        float ww[16] = { w0.x, w0.y, w0.z, w0.w, w1.x, w1.y, w1.z, w1.w,
                         w2.x, w2.y, w2.z, w2.w, w3.x, w3.y, w3.z, w3.w };
        int rowOff[4], colOff[4];
#pragma unroll
        for (int r = 0; r < 4; ++r) {
            rowOff[r] = min(gy0 + r, 24) * 25;
            colOff[r] = min(gx0 + r, 24);
        }
        int b625 = b * 625;
        float ax = 0.f, ay = 0.f;
#pragma unroll
        for (int cell = 0; cell < 16; ++cell) {
            int pix = b625 + rowOff[cell >> 2] + colOff[cell & 3];
            float2 v = *(const float2*)(feat + (size_t)pix * 256 + cbase);
            ax += ww[cell] * v.x;
            ay += ww[cell] * v.y;
        }
        sOut[(lane * 2) * 49 + bin] = f2bf(ax);
        sOut[(lane * 2 + 1) * 49 + bin] = f2bf(ay);
    }
    __syncthreads();
    const uint2* so = (const uint2*)sOut;
    uint2* dp = (uint2*)(P + (size_t)n * INF + q * 128 * 49);
    for (int i = tid; i < 128 * 49 / 4; i += 256) dp[i] = so[i];
}

// ---------------- split-K MFMA GEMM (BM=256=M) -> fp32 partial slabs --------
// A staged async via global_load_lds (zero VGPR). As unpadded 256x32 bf16 with
// XOR k-group swizzle: LDS[row][qq] = global k-group qq ^ ((row>>1)&3).
// B: one float4/thread -> f2bf -> padded Bs. 8 MFMA per k-step per wave.
template <int BN>
__global__ __launch_bounds__(256) void gemm_nt_part(
        const unsigned short* __restrict__ A, const float* __restrict__ Bw,
        float* __restrict__ Cpart, int N, int K, int kSteps) {
    constexpr int BM = 256;
    constexpr int LDB = 40;
    __shared__ unsigned short As[BM * 32];   // 16 KB, swizzled
    __shared__ unsigned short Bs[BN * LDB];  // 2.5 KB padded
    const int tid = threadIdx.x;
    const int lane = tid & 63;
    const int wave = tid >> 6;
    const int n0 = blockIdx.x * BN;
    const int k0 = blockIdx.z * kSteps * 32;
    const int quad = lane >> 4;
    const int l16 = lane & 15;
    constexpr int FM = 4, FN = BN / 16;

    floatx4 acc[FM][FN];
#pragma unroll
    for (int i = 0; i < FM; ++i)
#pragma unroll
        for (int j = 0; j < FN; ++j) acc[i][j] = (floatx4)0.f;

    // per-thread A staging descriptors (4 x 16B per k-step)
    const unsigned short* agp[4];
    void* alp[4];
#pragma unroll
    for (int i = 0; i < 4; ++i) {
        int idx = tid + i * 256;
        int row = idx >> 2;
        int qq = (idx & 3) ^ ((row >> 1) & 3);         // global-side swizzle
        agp[i] = A + (size_t)row * K + qq * 8;         // + kk at use
        alp[i] = (char*)As + ((size_t)i * 256 + wave * 64) * 16;  // wave-uniform
    }
    const int brow = tid >> 3, bq = tid & 7;
    const float* bgp = Bw + (size_t)(n0 + brow) * K + bq * 4;
    unsigned short* blp = Bs + brow * LDB + bq * 4;

    float4 bv = *(const float4*)(bgp + k0);
    for (int ks = 0; ks < kSteps; ++ks) {
        int kk = k0 + ks * 32;
        __syncthreads();                       // waves done reading LDS
#pragma unroll
        for (int i = 0; i < 4; ++i)
            async_copy16(agp[i] + kk, alp[i]); // async A -> LDS, no VGPR
        {
            ushort4 h;
            h.x = f2bf(bv.x); h.y = f2bf(bv.y); h.z = f2bf(bv.z); h.w = f2bf(bv.w);
            *(ushort4*)blp = h;
        }
        if (ks + 1 < kSteps) bv = *(const float4*)(bgp + kk + 32);  // prefetch
        __syncthreads();                       // vmcnt+lgkm drain
        short8 a[FM], bfr[FN];
#pragma unroll
        for (int i = 0; i < FM; ++i) {
            int r = wave * 64 + i * 16 + l16;
            int slot = quad ^ ((r >> 1) & 3);
            a[i] = *(const short8*)(As + r * 32 + slot * 8);
        }
#pragma unroll
        for (int j = 0; j < FN; ++j)
            bfr[j] = *(const short8*)(Bs + (j * 16 + l16) * LDB + quad * 8);
#pragma unroll
        for (int i = 0; i < FM; ++i)
#pragma unroll
            for (int j = 0; j < FN; ++j)
                acc[i][j] = __builtin_amdgcn_mfma_f32_16x16x32_bf16(a[i], bfr[j], acc[i][j], 0, 0, 0);
    }
    // epilogue: each row's BN*4 B span stored contiguously (full lines)
    float* Cp = Cpart + (size_t)blockIdx.z * BM * N;
#pragma unroll
    for (int i = 0; i < FM; ++i)
#pragma unroll
        for (int rr = 0; rr < 4; ++rr) {
            int row = wave * 64 + i * 16 + quad * 4 + rr;
            float* cr = Cp + (size_t)row * N + n0;
#pragma unroll
            for (int j = 0; j < FN; ++j)
                cr[j * 16 + l16] = acc[i][j][rr];
        }
}

// ---------------- reduce over Z + bias + optional relu + casts --------------
__global__ __launch_bounds__(256) void reduce_bias(
        const float* __restrict__ part, int zc, int mn4,
        const float* __restrict__ bias, int nmask, int relu,
        unsigned short* __restrict__ obf, float* __restrict__ of) {
    int idx = blockIdx.x * 256 + threadIdx.x;    // float4 index
    if (idx >= mn4) return;
    int idx4 = idx * 4;
    const float* bp = bias + (idx4 & nmask);
    float4 acc = *(const float4*)bp;
    const float4* p = (const float4*)part + idx;
    for (int z = 0; z < zc; ++z) {
        float4 v = p[(size_t)z * mn4];
        acc.x += v.x; acc.y += v.y; acc.z += v.z; acc.w += v.w;
    }
    if (relu) {
        acc.x = fmaxf(acc.x, 0.f); acc.y = fmaxf(acc.y, 0.f);
        acc.z = fmaxf(acc.z, 0.f); acc.w = fmaxf(acc.w, 0.f);
    }
    if (obf) {
        ushort4 h;
        h.x = f2bf(acc.x); h.y = f2bf(acc.y); h.z = f2bf(acc.z); h.w = f2bf(acc.w);
        *(ushort4*)(obf + idx4) = h;
    }
    if (of) *(float4*)(of + idx4) = acc;
}

// ---------------- G3: off = relu(h2) @ w3^T + b3  (256 x 98) ----------------
__global__ __launch_bounds__(128) void fc_small(
        const float* __restrict__ h2, const float* __restrict__ w3,
        const float* __restrict__ b3, float* __restrict__ out) {
    __shared__ float shl[1024];
    int n = blockIdx.x, tid = threadIdx.x;
    for (int i = tid; i < 1024; i += 128) shl[i] = fmaxf(h2[(size_t)n * 1024 + i], 0.f);
    __syncthreads();
    if (tid < 98) {
        float acc = b3[tid];
        const float* w = w3 + (size_t)tid * 1024;
        for (int k = 0; k < 1024; k += 4) {
            float4 wv = *(const float4*)(w + k);
            acc += shl[k] * wv.x + shl[k + 1] * wv.y + shl[k + 2] * wv.z + shl[k + 3] * wv.w;
        }
        out[n * 98 + tid] = acc;
    }
}

// ---------------- G6: out = relu(h4) @ box_w^T + box_b  (256 x 4) -----------
__global__ __launch_bounds__(64) void head_kernel(
        const float* __restrict__ h4, const float* __restrict__ bw,
        const float* __restrict__ bb, float* __restrict__ out) {
    int n = blockIdx.x, t = threadIdx.x;
    float a0 = 0, a1 = 0, a2 = 0, a3 = 0;
    for (int k = t; k < 512; k += 64) {
        float v = fmaxf(h4[(size_t)n * 512 + k], 0.f);
        a0 += v * bw[k]; a1 += v * bw[512 + k];
        a2 += v * bw[1024 + k]; a3 += v * bw[1536 + k];
    }
#pragma unroll
    for (int o = 32; o > 0; o >>= 1) {
        a0 += __shfl_down(a0, o); a1 += __shfl_down(a1, o);
        a2 += __shfl_down(a2, o); a3 += __shfl_down(a3, o);
    }
    if (t == 0) {
        out[n * 4 + 0] = a0 + bb[0]; out[n * 4 + 1] = a1 + bb[1];
        out[n * 4 + 2] = a2 + bb[2]; out[n * 4 + 3] = a3 + bb[3];
    }
}

// ---------------------------------------------------------------------------
extern "C" void kernel_launch(void* const* d_in, const int* in_sizes, int n_in,
                              void* d_out, int out_size, void* d_ws, size_t ws_size,
                              hipStream_t stream) {
    const float* x      = (const float*)d_in[0];
    const float* rois   = (const float*)d_in[1];
    const float* off_w1 = (const float*)d_in[2];
    const float* off_b1 = (const float*)d_in[3];
    const float* off_w2 = (const float*)d_in[4];
    const float* off_b2 = (const float*)d_in[5];
    const float* off_w3 = (const float*)d_in[6];
    const float* off_b3 = (const float*)d_in[7];
    const float* fc1_w  = (const float*)d_in[8];
    const float* fc1_b  = (const float*)d_in[9];
    const float* fc2_w  = (const float*)d_in[10];
    const float* fc2_b  = (const float*)d_in[11];
    const float* box_w  = (const float*)d_in[12];
    const float* box_b  = (const float*)d_in[13];
    float* out = (float*)d_out;

    char* ws = (char*)d_ws;
    size_t o = 0;
    auto carve = [&](size_t bytes) { char* p = ws + o; o += (bytes + 255) & ~(size_t)255; return p; };
    float*          xT   = (float*)carve((size_t)NB * 625 * 256 * 4);   // 5.12 MB
    unsigned short* P    = (unsigned short*)carve((size_t)NROI * INF * 2); // shared p0/p1
    unsigned short* h1b  = (unsigned short*)carve((size_t)NROI * DFC * 2);
    float*          h2   = (float*)carve((size_t)NROI * DFC * 4);
    float*          offb = (float*)carve((size_t)NROI * 98 * 4);
    unsigned short* h3b  = (unsigned short*)carve((size_t)NROI * FCC * 2);
    float*          h4   = (float*)carve((size_t)NROI * FCC * 4);
    float*          wbuf = (float*)carve((size_t)NROI * 49 * 16 * 4);   // 803 KB
    int*            bbuf = (int*)carve((size_t)NROI * 49 * 4);
    size_t fixed = o;
    const size_t SLAB = (size_t)NROI * DFC * 4;   // 1 MB (G1/G2-sized slice)
    int zg1;                        // tier on ws_size (constant -> graph-safe)
    if      (ws_size >= fixed + 28 * SLAB) zg1 = 28;
    else if (ws_size >= fixed + 14 * SLAB) zg1 = 14;
    else                                   zg1 = 7;
    int zg2 = (zg1 >= 8) ? 8 : 4;   // divides 32 (G2) and 16 (G5)
    float* part = (float*)carve((size_t)zg1 * SLAB);

    // 1. channels-last transpose of x
    transpose_kernel<<<dim3(20, 8, 8), 256, 0, stream>>>(x, xT);
    // 2. pool pass 0 (zero offsets)
    pool_prep<<<49, 256, 0, stream>>>(rois, nullptr, 0, wbuf, bbuf);
    pool_gather<<<dim3(2, NROI), 256, 0, stream>>>(xT, wbuf, bbuf, P);
    // 3. G1 partials + reduce(+b1+relu) -> h1b     (256x12544x1024)
    gemm_nt_part<32><<<dim3(32, 1, zg1), 256, 0, stream>>>(P, off_w1, part, DFC, INF, 392 / zg1);
    reduce_bias<<<256, 256, 0, stream>>>(part, zg1, NROI * DFC / 4, off_b1, DFC - 1, 1, h1b, nullptr);
    // 4. G2 partials + reduce(+b2) -> h2 (fp32; fc_small applies relu)
    gemm_nt_part<32><<<dim3(32, 1, zg2), 256, 0, stream>>>(h1b, off_w2, part, DFC, DFC, 32 / zg2);
    reduce_bias<<<256, 256, 0, stream>>>(part, zg2, NROI * DFC / 4, off_b2, DFC - 1, 0, nullptr, h2);
    // 5. G3: offb = relu(h2) @ w3^T + b3
    fc_small<<<NROI, 128, 0, stream>>>(h2, off_w3, off_b3, offb);
    // 6. pool pass 1 (learned offsets), reuses P
    pool_prep<<<49, 256, 0, stream>>>(rois, offb, 1, wbuf, bbuf);
    pool_gather<<<dim3(2, NROI), 256, 0, stream>>>(xT, wbuf, bbuf, P);
    // 7. G4 partials + reduce(+fc1_b+relu) -> h3b  (256x12544x512)
    gemm_nt_part<32><<<dim3(16, 1, zg1), 256, 0, stream>>>(P, fc1_w, part, FCC, INF, 392 / zg1);
    reduce_bias<<<128, 256, 0, stream>>>(part, zg1, NROI * FCC / 4, fc1_b, FCC - 1, 1, h3b, nullptr);
    // 8. G5 partials + reduce(+fc2_b) -> h4 (fp32; head applies relu)
    gemm_nt_part<32><<<dim3(16, 1, zg2), 256, 0, stream>>>(h3b, fc2_w, part, FCC, FCC, 16 / zg2);
    reduce_bias<<<128, 256, 0, stream>>>(part, zg2, NROI * FCC / 4, fc2_b, FCC - 1, 0, nullptr, h4);
    // 9. G6: out = relu(h4) @ box_w^T + box_b
    head_kernel<<<NROI, 64, 0, stream>>>(h4, box_w, box_b, out);
}